// Round 5
// baseline (160.817 us; speedup 1.0000x reference)
//
#include <hip/hip_runtime.h>
#include <cstddef>
#include <cstdint>

#define NOBJ   16
#define FEAT   512
#define VIS    2048
#define NTGT   24
#define MROWS  4096
#define EROWS  32768

typedef __attribute__((ext_vector_type(8))) short short8;
typedef __attribute__((ext_vector_type(4))) float f32x4;

__device__ __forceinline__ unsigned short f2bf(float f) {
    union { float f; unsigned int i; } v; v.f = f;
    const unsigned int x = v.i;
    return (unsigned short)((x + 0x7fffu + ((x >> 16) & 1u)) >> 16);  // RTNE
}

// async 16B global -> LDS (dest: wave-uniform base + lane*16)
__device__ __forceinline__ void gload16(const unsigned short* g, unsigned short* l) {
    __builtin_amdgcn_global_load_lds(
        (const __attribute__((address_space(1))) unsigned int*)(const void*)g,
        (__attribute__((address_space(3))) unsigned int*)(void*)l, 16, 0, 0);
}

// ---------------------------------------------------------------------------
// prep1: [0,1024) wtrans | [1024,1154) wchain1 | [1154,2178) src f32->bf16
__global__ __launch_bounds__(256)
void prep1(const float* __restrict__ w1, unsigned short* __restrict__ w1t,
           const float* __restrict__ wf, const float* __restrict__ bfv,
           const float* __restrict__ wr, float* __restrict__ t1,
           const float* __restrict__ src, unsigned short* __restrict__ srcb) {
    __shared__ float shbuf[FEAT * NTGT];   // 48 KB
    const int b   = blockIdx.x;
    const int tid = threadIdx.x;
    if (b < 1024) {
        float (*tile)[33] = (float(*)[33])shbuf;
        const int k0 = (b & 63) * 32;
        const int n0 = (b >> 6) * 32;
        const int tx = tid & 31, ty = tid >> 5;
        #pragma unroll
        for (int r = 0; r < 32; r += 8)
            tile[ty + r][tx] = w1[(size_t)(k0 + ty + r) * FEAT + n0 + tx];
        __syncthreads();
        #pragma unroll
        for (int r = 0; r < 32; r += 8)
            w1t[(size_t)(n0 + ty + r) * VIS + k0 + tx] = f2bf(tile[tx][ty + r]);
    } else if (b < 1154) {
        const int bb = b - 1024;           // 0..129
        const int h  = bb & 1;
        const float* wrh = wr + (size_t)h * FEAT * NTGT;
        for (int idx = tid; idx < FEAT * NTGT; idx += 256)
            shbuf[idx] = wrh[idx];
        __syncthreads();
        const int c    = tid & 31;
        const int krow = (bb >> 1) * 8 + (tid >> 5);   // 0..519
        if (krow > 512) return;
        const float* rowp = (krow < 512) ? (wf + (size_t)krow * FEAT) : bfv;
        const int ce = (c < NTGT) ? c : NTGT - 1;
        float s = 0.f;
        #pragma unroll 8
        for (int j = 0; j < FEAT; ++j)
            s = fmaf(rowp[j], shbuf[j * NTGT + ce], s);
        if (c < NTGT) t1[((size_t)h * 513 + krow) * 32 + c] = s;
    } else {
        // src convert: 1024 blocks x 8192 elements
        const int bb = b - 1154;
        #pragma unroll
        for (int q = 0; q < 4; ++q) {
            const size_t i = (size_t)bb * 8192 + q * 2048 + tid * 8;
            const float4 a = *reinterpret_cast<const float4*>(src + i);
            const float4 c = *reinterpret_cast<const float4*>(src + i + 4);
            short8 o;
            o[0] = (short)f2bf(a.x); o[1] = (short)f2bf(a.y);
            o[2] = (short)f2bf(a.z); o[3] = (short)f2bf(a.w);
            o[4] = (short)f2bf(c.x); o[5] = (short)f2bf(c.y);
            o[6] = (short)f2bf(c.z); o[7] = (short)f2bf(c.w);
            *reinterpret_cast<short8*>(srcb + i) = o;
        }
    }
}

// ---------------------------------------------------------------------------
// prep2: [0,1024) zero P | [1024,1154) wchain2
__global__ __launch_bounds__(256)
void prep2(const float* __restrict__ w2, const float* __restrict__ b2,
           const float* __restrict__ t1, unsigned short* __restrict__ wABt,
           float* __restrict__ biasAB, float* __restrict__ P) {
    __shared__ float shbuf[FEAT * NTGT];   // 48 KB
    const int b   = blockIdx.x;
    const int tid = threadIdx.x;
    if (b < 1024) {
        P[(size_t)b * 256 + tid] = 0.f;    // 4096*64 f32
        return;
    }
    const int bb = b - 1024;
    const int h  = bb & 1;
    for (int idx = tid; idx < FEAT * NTGT; idx += 256) {
        const int row = idx / NTGT, col = idx - row * NTGT;
        shbuf[idx] = t1[((size_t)h * 513 + row) * 32 + col];
    }
    __syncthreads();
    const int c = tid & 31;
    const int r = (bb >> 1) * 8 + (tid >> 5);
    if (r > 512) return;
    const float* rowp = (r < 512) ? (w2 + (size_t)r * FEAT) : b2;
    const int ce = (c < NTGT) ? c : NTGT - 1;
    float s = 0.f;
    #pragma unroll 8
    for (int k = 0; k < FEAT; ++k)
        s = fmaf(rowp[k], shbuf[k * NTGT + ce], s);
    if (c < NTGT) {
        const int q = h * NTGT + c;
        if (r < 512) wABt[(size_t)q * FEAT + r] = f2bf(s);
        else         biasAB[q] = s + t1[((size_t)h * 513 + 512) * 32 + c];
    }
}

// ---------------------------------------------------------------------------
// gemm1f: per 64x32 tile: h = relu(srcb @ w1t^T + b1), then fused projection
// atomicAdd P[64x48] += h_tile @ wABt[:, n-slice]^T.
// BM=64 BN=32 BK=64, grid 1024 (4 blocks/CU), all staging via global_load_lds
// (linear LDS dest, inverse-swizzled global source; read applies XOR).
__global__ __launch_bounds__(256)
void gemm1f(const unsigned short* __restrict__ srcb, const unsigned short* __restrict__ w1t,
            const float* __restrict__ b1, const unsigned short* __restrict__ wABt,
            float* __restrict__ P) {
    __shared__ __align__(16) unsigned short As[2][64 * 64];  // 16 KB
    __shared__ __align__(16) unsigned short Bs[2][32 * 64];  //  8 KB

    const int bid = blockIdx.x;
    const int xcd = bid & 7;
    const int k8  = bid >> 3;               // 0..127
    const int xb  = k8 & 15;                // n-panel 0..15
    const int yb  = (xcd << 3) | (k8 >> 4); // m-panel 0..63
    const int m0 = yb * 64;
    const int n0 = xb * 32;

    const int tid  = threadIdx.x;
    const int lane = tid & 63;
    const int wid  = tid >> 6;
    const int wr = wid >> 1, wc = wid & 1;

    // per-lane global source chunk (inverse swizzle), wave-uniform LDS bases
    const int aRow0 = tid >> 3, aCd0 = (tid & 7) ^ (aRow0 & 7);
    const int s1i   = 256 + tid;
    const int aRow1 = s1i >> 3, aCd1 = (s1i & 7) ^ (aRow1 & 7);
    const int bN    = tid >> 3, bCd = (tid & 7) ^ (bN & 7);
    const size_t aOff0 = (size_t)(m0 + aRow0) * VIS + (aCd0 << 3);
    const size_t aOff1 = (size_t)(m0 + aRow1) * VIS + (aCd1 << 3);
    const size_t bOff  = (size_t)(n0 + bN) * VIS + (bCd << 3);
    const int ldsA0 = (wid * 64) << 3;          // slot*8 ushorts
    const int ldsA1 = (256 + wid * 64) << 3;
    const int ldsB  = (wid * 64) << 3;

    f32x4 acc[2] = {};

    // prologue: stage tile 0
    gload16(srcb + aOff0, &As[0][ldsA0]);
    gload16(srcb + aOff1, &As[0][ldsA1]);
    gload16(w1t + bOff,  &Bs[0][ldsB]);
    __syncthreads();

    int cur = 0;
    for (int t = 0; t < VIS / 64; ++t) {
        if (t + 1 < VIS / 64) {               // issue next-tile loads first
            const int kn = (t + 1) * 64;
            gload16(srcb + aOff0 + kn, &As[cur ^ 1][ldsA0]);
            gload16(srcb + aOff1 + kn, &As[cur ^ 1][ldsA1]);
            gload16(w1t + bOff + kn,  &Bs[cur ^ 1][ldsB]);
        }
        #pragma unroll
        for (int k2 = 0; k2 < 2; ++k2) {
            short8 af[2], bfr;
            #pragma unroll
            for (int fr = 0; fr < 2; ++fr) {
                const int row = wr * 32 + fr * 16 + (lane & 15);
                const int cw  = ((k2 << 2) + (lane >> 4)) ^ (row & 7);
                af[fr] = *reinterpret_cast<const short8*>(&As[cur][(row << 6) + (cw << 3)]);
            }
            {
                const int n  = wc * 16 + (lane & 15);
                const int cw = ((k2 << 2) + (lane >> 4)) ^ (n & 7);
                bfr = *reinterpret_cast<const short8*>(&Bs[cur][(n << 6) + (cw << 3)]);
            }
            #pragma unroll
            for (int fr = 0; fr < 2; ++fr)
                acc[fr] = __builtin_amdgcn_mfma_f32_16x16x32_bf16(af[fr], bfr, acc[fr], 0, 0, 0);
        }
        __syncthreads();                      // drains vmcnt+lgkm; next buf ready
        cur ^= 1;
    }

    // ---------------- fused projection epilogue ----------------
    short8 bq[3];
    #pragma unroll
    for (int t3 = 0; t3 < 3; ++t3)
        bq[t3] = *reinterpret_cast<const short8*>(
            wABt + (size_t)(t3 * 16 + (lane & 15)) * FEAT + n0 + ((lane >> 4) << 3));

    unsigned short* Ht = &As[0][0];           // 64x40 bf16 (reuse)
    {
        const int nl   = wc * 16 + (lane & 15);
        const float bias = b1[n0 + nl];
        #pragma unroll
        for (int fr = 0; fr < 2; ++fr) {
            const int ml = wr * 32 + fr * 16 + ((lane >> 4) << 2);
            #pragma unroll
            for (int r = 0; r < 4; ++r) {
                const float v = fmaxf(acc[fr][r] + bias, 0.f);
                Ht[(ml + r) * 40 + nl] = f2bf(v);
            }
        }
    }
    __syncthreads();

    short8 aep;
    {
        const int m = wid * 16 + (lane & 15);
        aep = *reinterpret_cast<const short8*>(&Ht[m * 40 + ((lane >> 4) << 3)]);
    }
    const f32x4 pz = {0.f, 0.f, 0.f, 0.f};
    #pragma unroll
    for (int t3 = 0; t3 < 3; ++t3) {
        f32x4 pp = __builtin_amdgcn_mfma_f32_16x16x32_bf16(aep, bq[t3], pz, 0, 0, 0);
        const int q  = t3 * 16 + (lane & 15);
        const int mb = m0 + wid * 16 + ((lane >> 4) << 2);
        #pragma unroll
        for (int r = 0; r < 4; ++r)
            atomicAdd(&P[(size_t)(mb + r) * 64 + q], pp[r]);
    }
}

// ---------------------------------------------------------------------------
__global__ __launch_bounds__(256)
void out_loss_kernel(const float* __restrict__ P, const float* __restrict__ br,
                     const float* __restrict__ biasAB, const int* __restrict__ tgt,
                     float* __restrict__ out, float* __restrict__ out_tgt,
                     float* __restrict__ partials) {
    __shared__ float sm[32][49];
    const int bt  = blockIdx.x;
    const int tid = threadIdx.x;
    for (int idx = tid; idx < 32 * 48; idx += 256) {
        const int row = idx / 48, col = idx - row * 48;
        sm[row][col] = P[(size_t)(bt * 32 + row) * 64 + col];
    }
    __syncthreads();

    const int r  = bt * 256 + tid;
    const int i  = tid >> 4, j = tid & 15;
    const int tg = tgt[r];

    float vals[NTGT];
    float mx = -1e30f, vtg = 0.f;
    #pragma unroll
    for (int t = 0; t < NTGT; ++t) {
        const float cv = br[t] + biasAB[t] + biasAB[24 + t];
        const float v  = sm[i][t] + sm[16 + j][24 + t] + cv;
        vals[t] = v;
        mx = fmaxf(mx, v);
        if (t == tg) vtg = v;
    }
    float se = 0.f;
    #pragma unroll
    for (int t = 0; t < NTGT; ++t) se += expf(vals[t] - mx);
    const float lse = mx + logf(se);

    float4* o4 = reinterpret_cast<float4*>(out + (size_t)r * NTGT);
    #pragma unroll
    for (int q = 0; q < 6; ++q)
        o4[q] = make_float4(vals[q * 4], vals[q * 4 + 1], vals[q * 4 + 2], vals[q * 4 + 3]);
    out_tgt[r] = (float)tg;

    const float wcl = (tg == 0) ? 1.f : 100.f;
    float p1 = wcl * (lse - vtg);
    float p2 = wcl;
    #pragma unroll
    for (int off = 32; off > 0; off >>= 1) {
        p1 += __shfl_down(p1, off);
        p2 += __shfl_down(p2, off);
    }
    __shared__ float s1[4], s2[4];
    const int lane = tid & 63, wv = tid >> 6;
    if (lane == 0) { s1[wv] = p1; s2[wv] = p2; }
    __syncthreads();
    if (tid == 0) {
        partials[bt]       = s1[0] + s1[1] + s1[2] + s1[3];
        partials[128 + bt] = s2[0] + s2[1] + s2[2] + s2[3];
    }
}

__global__ void final_loss(const float* __restrict__ partials, float* __restrict__ loss) {
    const int t = threadIdx.x;                       // 64 threads
    float a = partials[t] + partials[t + 64];
    float b = partials[128 + t] + partials[192 + t];
    #pragma unroll
    for (int off = 32; off > 0; off >>= 1) {
        a += __shfl_down(a, off);
        b += __shfl_down(b, off);
    }
    if (t == 0) loss[0] = a / b;
}

// ---------------------------------------------------------------------------
extern "C" void kernel_launch(void* const* d_in, const int* in_sizes, int n_in,
                              void* d_out, int out_size, void* d_ws, size_t ws_size,
                              hipStream_t stream) {
    const float* src = (const float*)d_in[0];
    const int*   tgt = (const int*)d_in[1];
    const float* w1  = (const float*)d_in[2];
    const float* b1  = (const float*)d_in[3];
    const float* w2  = (const float*)d_in[4];
    const float* b2  = (const float*)d_in[5];
    const float* wf  = (const float*)d_in[6];
    const float* bfv = (const float*)d_in[7];
    const float* wr  = (const float*)d_in[8];
    const float* br  = (const float*)d_in[9];

    float* ws = (float*)d_ws;
    unsigned short* w1t   = (unsigned short*)(ws);             // 512x2048 bf16
    unsigned short* srcb  = (unsigned short*)(ws + 524288);    // 4096x2048 bf16
    float*          t1    = ws + 4718592;                      // 2*513*32 f32
    unsigned short* wABt  = (unsigned short*)(ws + 4751424);   // 48x512 bf16
    float*          biasAB = ws + 4763712;                     // 48 (+pad)
    float*          P     = ws + 4763776;                      // 4096x64 f32
    float*          parts = ws + 5025920;                      // 256 f32

    float* out_logits = (float*)d_out;
    float* out_tgt    = out_logits + (size_t)EROWS * NTGT;
    float* out_lossp  = out_tgt + EROWS;

    prep1<<<2178, 256, 0, stream>>>(w1, w1t, wf, bfv, wr, t1, src, srcb);
    prep2<<<1154, 256, 0, stream>>>(w2, b2, t1, wABt, biasAB, P);
    gemm1f<<<1024, 256, 0, stream>>>(srcb, w1t, b1, wABt, P);
    out_loss_kernel<<<128, 256, 0, stream>>>(P, br, biasAB, tgt,
                                             out_logits, out_tgt, parts);
    final_loss<<<1, 64, 0, stream>>>(parts, out_lossp);
}